// Round 1
// baseline (302.226 us; speedup 1.0000x reference)
//
#include <hip/hip_runtime.h>

// DropBlock + LIF forward.
// x: [T*bs, C, H, W] = [160, 64, 64, 64] f32
// mask_rand: [T*bs, H, W] f32
// out: [160, 64, 64, 64] f32
//
// Stage 1: bm = 1 - maxpool7x7(mask_rand < gamma)  -> d_ws (f32, 2.6 MB)
// Stage 2: per-element LIF recurrence over T=5, o_t = spike(u) * bm_t.

#define TSTEPS 5
#define BSZ 32
#define CHN 64
#define HH 64
#define WW 64

__global__ __launch_bounds__(256) void bm_kernel(const float* __restrict__ mr,
                                                 float* __restrict__ bm,
                                                 int total) {
    int idx = blockIdx.x * blockDim.x + threadIdx.x;  // over N*H*W
    if (idx >= total) return;
    int w = idx & (WW - 1);
    int h = (idx >> 6) & (HH - 1);
    int n = idx >> 12;
    // gamma computed in double then cast, matching JAX's weak-type promotion
    const float GAMMA = (float)(0.1 / 49.0);
    const float* base = mr + (size_t)n * (HH * WW);
    int h0 = h - 3 < 0 ? 0 : h - 3;
    int h1 = h + 3 > HH - 1 ? HH - 1 : h + 3;
    int w0 = w - 3 < 0 ? 0 : w - 3;
    int w1 = w + 3 > WW - 1 ? WW - 1 : w + 3;
    bool drop = false;
    for (int hh = h0; hh <= h1; ++hh) {
        const float* row = base + hh * WW;
        for (int ww = w0; ww <= w1; ++ww)
            drop = drop || (row[ww] < GAMMA);
    }
    bm[idx] = drop ? 0.0f : 1.0f;
}

__global__ __launch_bounds__(256) void lif_kernel(const float* __restrict__ x,
                                                  const float* __restrict__ bm,
                                                  float* __restrict__ o) {
    const int HW4 = HH * WW / 4;  // 1024 float4 groups per plane
    int idx = blockIdx.x * blockDim.x + threadIdx.x;  // [0, BSZ*CHN*HW4)
    int hw4 = idx & (HW4 - 1);
    int c = (idx >> 10) & (CHN - 1);
    int b = idx >> 16;
    if (b >= BSZ) return;

    size_t xoff = (((size_t)b * CHN + c) * (size_t)(HH * WW)) + (size_t)hw4 * 4;
    size_t moff = ((size_t)b * (size_t)(HH * WW)) + (size_t)hw4 * 4;
    const size_t XT = (size_t)BSZ * CHN * HH * WW;  // x time stride
    const size_t MT = (size_t)BSZ * HH * WW;        // bm time stride

    float4 u = make_float4(0.f, 0.f, 0.f, 0.f);
#pragma unroll
    for (int t = 0; t < TSTEPS; ++t) {
        float4 xv = *(const float4*)(x + xoff + (size_t)t * XT);
        float4 mv = *(const float4*)(bm + moff + (size_t)t * MT);
        // u = tau*u*(1-spike(u)) + x  ==  (u>1 ? 0 : 0.5*u) + x   (bitwise equal)
        u.x = (u.x > 1.0f ? 0.0f : 0.5f * u.x) + xv.x;
        u.y = (u.y > 1.0f ? 0.0f : 0.5f * u.y) + xv.y;
        u.z = (u.z > 1.0f ? 0.0f : 0.5f * u.z) + xv.z;
        u.w = (u.w > 1.0f ? 0.0f : 0.5f * u.w) + xv.w;
        float4 ov;
        ov.x = (u.x > 1.0f) ? mv.x : 0.0f;
        ov.y = (u.y > 1.0f) ? mv.y : 0.0f;
        ov.z = (u.z > 1.0f) ? mv.z : 0.0f;
        ov.w = (u.w > 1.0f) ? mv.w : 0.0f;
        *(float4*)(o + xoff + (size_t)t * XT) = ov;
    }
}

extern "C" void kernel_launch(void* const* d_in, const int* in_sizes, int n_in,
                              void* d_out, int out_size, void* d_ws, size_t ws_size,
                              hipStream_t stream) {
    const float* x = (const float*)d_in[0];
    const float* mask_rand = (const float*)d_in[1];
    float* out = (float*)d_out;
    float* bm = (float*)d_ws;  // TSTEPS*BSZ*HH*WW floats = 2.6 MB

    const int bm_total = TSTEPS * BSZ * HH * WW;        // 655,360
    const int lif_threads = BSZ * CHN * (HH * WW / 4);  // 2,097,152

    bm_kernel<<<(bm_total + 255) / 256, 256, 0, stream>>>(mask_rand, bm, bm_total);
    lif_kernel<<<(lif_threads + 255) / 256, 256, 0, stream>>>(x, bm, out);
}

// Round 3
// 279.963 us; speedup vs baseline: 1.0795x; 1.0795x over previous
//
#include <hip/hip_runtime.h>

// DropBlock + LIF forward.
// x: [T*bs, C, H, W] = [160, 64, 64, 64] f32
// mask_rand: [T*bs, H, W] f32
// out: [160, 64, 64, 64] f32
//
// Stage 1 (bm_kernel): bm = 1 - maxpool7x7(mask_rand < gamma) -> d_ws (f32)
//   One wave per output row: 7 clipped vertical loads/lane -> per-lane OR,
//   __ballot -> 64-bit row mask (W dimension = 64 bits), horizontal dilation
//   as bit smear +/-3. Replaces the 49-tap window scan.
// Stage 2 (lif_kernel): per-element LIF recurrence over T=5,
//   o_t = spike(u) * bm_t. Non-temporal v4f streaming on x/o.

#define TSTEPS 5
#define BSZ 32
#define CHN 64
#define HH 64
#define WW 64

// native clang vector type — required by __builtin_nontemporal_load/store
typedef float v4f __attribute__((ext_vector_type(4)));

__global__ __launch_bounds__(256) void bm_kernel(const float* __restrict__ mr,
                                                 float* __restrict__ bm) {
    // one wave (64 lanes) per output row; 4 waves per block
    const float GAMMA = (float)(0.1 / 49.0);
    int wave = blockIdx.x * 4 + (threadIdx.x >> 6);  // row id in [0, N*HH)
    int lane = threadIdx.x & 63;                     // pixel w
    int h = wave & (HH - 1);
    int n = wave >> 6;  // plane id in [0, TSTEPS*BSZ)

    const float* base = mr + (size_t)n * (HH * WW) + lane;
    bool drop = false;
#pragma unroll
    for (int dh = -3; dh <= 3; ++dh) {
        int hh = h + dh;
        if (hh >= 0 && hh < HH) drop = drop || (base[hh * WW] < GAMMA);
    }
    unsigned long long m = __ballot(drop);  // vertical dilation done; bit w = column drop
    // horizontal dilation +/-3 (bit shifts clip at row boundary naturally)
    unsigned long long s = m | (m << 1) | (m << 2) | (m << 3)
                             | (m >> 1) | (m >> 2) | (m >> 3);
    bm[(size_t)wave * WW + lane] = ((s >> lane) & 1ull) ? 0.0f : 1.0f;
}

__global__ __launch_bounds__(256) void lif_kernel(const float* __restrict__ x,
                                                  const float* __restrict__ bm,
                                                  float* __restrict__ o) {
    const int HW4 = HH * WW / 4;  // 1024 float4 groups per plane
    int idx = blockIdx.x * blockDim.x + threadIdx.x;  // [0, BSZ*CHN*HW4)
    int hw4 = idx & (HW4 - 1);
    int c = (idx >> 10) & (CHN - 1);
    int b = idx >> 16;
    if (b >= BSZ) return;

    size_t xoff = (((size_t)b * CHN + c) * (size_t)(HH * WW)) + (size_t)hw4 * 4;
    size_t moff = ((size_t)b * (size_t)(HH * WW)) + (size_t)hw4 * 4;
    const size_t XT = (size_t)BSZ * CHN * HH * WW;  // x time stride
    const size_t MT = (size_t)BSZ * HH * WW;        // bm time stride

    v4f u = {0.f, 0.f, 0.f, 0.f};
#pragma unroll
    for (int t = 0; t < TSTEPS; ++t) {
        // x is streamed once -> non-temporal; bm is reused 64x across C -> cached
        v4f xv = __builtin_nontemporal_load((const v4f*)(x + xoff + (size_t)t * XT));
        v4f mv = *(const v4f*)(bm + moff + (size_t)t * MT);
        // u = tau*u*(1-spike(u)) + x  ==  (u>1 ? 0 : 0.5*u) + x   (bitwise equal)
        u.x = (u.x > 1.0f ? 0.0f : 0.5f * u.x) + xv.x;
        u.y = (u.y > 1.0f ? 0.0f : 0.5f * u.y) + xv.y;
        u.z = (u.z > 1.0f ? 0.0f : 0.5f * u.z) + xv.z;
        u.w = (u.w > 1.0f ? 0.0f : 0.5f * u.w) + xv.w;
        v4f ov;
        ov.x = (u.x > 1.0f) ? mv.x : 0.0f;
        ov.y = (u.y > 1.0f) ? mv.y : 0.0f;
        ov.z = (u.z > 1.0f) ? mv.z : 0.0f;
        ov.w = (u.w > 1.0f) ? mv.w : 0.0f;
        __builtin_nontemporal_store(ov, (v4f*)(o + xoff + (size_t)t * XT));
    }
}

extern "C" void kernel_launch(void* const* d_in, const int* in_sizes, int n_in,
                              void* d_out, int out_size, void* d_ws, size_t ws_size,
                              hipStream_t stream) {
    const float* x = (const float*)d_in[0];
    const float* mask_rand = (const float*)d_in[1];
    float* out = (float*)d_out;
    float* bm = (float*)d_ws;  // TSTEPS*BSZ*HH*WW floats = 2.6 MB

    const int bm_rows = TSTEPS * BSZ * HH;              // 10240 rows (1 wave each)
    const int lif_threads = BSZ * CHN * (HH * WW / 4);  // 2,097,152

    bm_kernel<<<bm_rows / 4, 256, 0, stream>>>(mask_rand, bm);
    lif_kernel<<<(lif_threads + 255) / 256, 256, 0, stream>>>(x, bm, out);
}